// Round 1
// 997.769 us; speedup vs baseline: 1.0214x; 1.0214x over previous
//
#include <hip/hip_runtime.h>
#include <math.h>

#define BKS 60      // B*K sequences
#define TL  1000    // T
#define NF  128     // N features
#define SD  12      // state dim S
#define RD  8       // dt rank
#define NCH 32      // scan chunks (last partial: 31*32=992, +8)
#define CLEN 32     // chunk length -> 38.4KB LDS -> 4 blocks/CU
#define NTOK (BKS*TL)
#define MT  64      // GEMM token tile
#define NBLK ((NTOK + MT - 1)/MT)   // 938
#define XSP 68      // xs [n][t] stride
#define WSP 260     // in_proj w_lds stride (256+4)
#define GWS 132     // 128-out w_lds stride (128+4)
#define LNP 129     // cross_ln LDS stride (odd -> conflict-free)

__device__ __forceinline__ float siluf(float x){ return x / (1.f + __expf(-x)); }
__device__ __forceinline__ float softplusf(float x){
  if (x > 20.f) return x;
  float e = __expf(x);
  return (x < -20.f) ? e : __logf(1.f + e);
}

// ---- K0: x (B,N,T,K) -> seq (B*K, T, N), one block per (b,t)
__global__ __launch_bounds__(256) void k_ingest(const float* __restrict__ x, float* __restrict__ seq){
  const int b = blockIdx.x / TL, t = blockIdx.x % TL;
  __shared__ float tile[30*NF];
  for (int e = threadIdx.x; e < 30*NF; e += 256){
    int n = e / 30, k = e - n*30;
    tile[k*NF + n] = x[((size_t)(b*NF + n)*TL + t)*30 + k];
  }
  __syncthreads();
  const size_t base = ((size_t)b*30)*TL*NF + (size_t)t*NF;
  for (int e = threadIdx.x; e < 30*NF; e += 256){
    int k = e >> 7, n = e & 127;
    seq[base + (size_t)k*TL*NF + n] = tile[e];
  }
}

// ---- K1: LayerNorm + in_proj. 64 tok/block, 256 thr. Output tile SPLIT 4+4:
// thread owns outputs {o8*4..+3} (-> xcr) and {128+o8*4..+3} (-> zb), so both LDS
// w-reads are 16B-lane-stride contiguous float4s (2-way max = free).
__global__ __launch_bounds__(256) void k_ln_inproj(
    const float* __restrict__ seq, const float* __restrict__ lnw, const float* __restrict__ lnb,
    const float* __restrict__ iw, const float* __restrict__ ib,
    float* __restrict__ xcr, float* __restrict__ zb){
  __shared__ float xs[NF*XSP];    // [k][t]
  __shared__ float wl[16*WSP];    // [kl][o]
  const int tid = threadIdx.x;
  const int tok0 = blockIdx.x * MT;

  {
    const int j = tid >> 4, l16 = tid & 15;
    for (int it = 0; it < 4; ++it){
      const int t = j + 16*it;
      const int tok = tok0 + t;
      float v[8]; float s = 0.f, s2 = 0.f;
      if (tok < NTOK){
        const float* sp = seq + (size_t)tok*NF;
        #pragma unroll
        for (int i = 0; i < 8; ++i){ float f = sp[l16 + 16*i]; v[i] = f; s += f; s2 += f*f; }
      } else {
        #pragma unroll
        for (int i = 0; i < 8; ++i) v[i] = 0.f;
      }
      #pragma unroll
      for (int m = 1; m < 16; m <<= 1){ s += __shfl_xor(s, m, 64); s2 += __shfl_xor(s2, m, 64); }
      const float mean = s * (1.f/128.f);
      const float rstd = rsqrtf(s2*(1.f/128.f) - mean*mean + 1e-5f);
      #pragma unroll
      for (int i = 0; i < 8; ++i){
        int n = l16 + 16*i;
        xs[n*XSP + t] = (v[i]-mean)*rstd*lnw[n] + lnb[n];
      }
    }
  }

  const int o8 = tid & 31, t8 = tid >> 5;
  float acc[8][8];
  #pragma unroll
  for (int o = 0; o < 8; ++o)
    #pragma unroll
    for (int t = 0; t < 8; ++t) acc[o][t] = 0.f;

  for (int kt = 0; kt < 8; ++kt){
    __syncthreads();
    {
      const int ch = tid & 3, row = tid >> 2;
      #pragma unroll
      for (int p = 0; p < 4; ++p){
        const int o = row + 64*p;
        const float4 w4 = *(const float4*)(iw + (size_t)o*NF + kt*16 + ch*4);
        const int kl = ch*4;
        wl[(kl+0)*WSP + o] = w4.x;
        wl[(kl+1)*WSP + o] = w4.y;
        wl[(kl+2)*WSP + o] = w4.z;
        wl[(kl+3)*WSP + o] = w4.w;
      }
    }
    __syncthreads();
    for (int kl = 0; kl < 16; ++kl){
      const int kg = kt*16 + kl;
      const float4 wa = *(const float4*)&wl[kl*WSP + o8*4];          // outs o8*4..+3
      const float4 wb = *(const float4*)&wl[kl*WSP + 128 + o8*4];    // outs 128+o8*4..+3
      const float4 xa = *(const float4*)&xs[kg*XSP + t8*8];
      const float4 xb = *(const float4*)&xs[kg*XSP + t8*8 + 4];
      const float wv[8] = {wa.x,wa.y,wa.z,wa.w, wb.x,wb.y,wb.z,wb.w};
      const float xv[8] = {xa.x,xa.y,xa.z,xa.w, xb.x,xb.y,xb.z,xb.w};
      #pragma unroll
      for (int o = 0; o < 8; ++o)
        #pragma unroll
        for (int t = 0; t < 8; ++t)
          acc[o][t] = fmaf(wv[o], xv[t], acc[o][t]);
    }
  }

  float bo[8];
  #pragma unroll
  for (int i = 0; i < 4; ++i){ bo[i] = ib[o8*4 + i]; bo[4+i] = ib[128 + o8*4 + i]; }
  #pragma unroll
  for (int j = 0; j < 8; ++j){
    const int tok = tok0 + t8*8 + j;
    if (tok >= NTOK) break;
    float4 r0, r1;
    r0.x = acc[0][j]+bo[0]; r0.y = acc[1][j]+bo[1]; r0.z = acc[2][j]+bo[2]; r0.w = acc[3][j]+bo[3];
    r1.x = acc[4][j]+bo[4]; r1.y = acc[5][j]+bo[5]; r1.z = acc[6][j]+bo[6]; r1.w = acc[7][j]+bo[7];
    *(float4*)(xcr + (size_t)tok*NF + o8*4) = r0;
    *(float4*)(zb  + (size_t)tok*NF + o8*4) = r1;
  }
}

// ---- K2f (R12 rewrite): conv+silu -> x-proj -> dt/B/C -> scan pass 1.
// Same algorithm / LDS footprint (38.4KB, 4 blocks/CU) as R10; access patterns
// vectorized to cut LDS-pipe serialization (was ~47us of b32 reads):
//   - stage/conv: float4 global + b128 LDS
//   - xproj: 4o x 4t x 4-way K split (32 b128 reads/thread, was 128); partials
//     in sdbc4 aliased over dead sxr region; b128 reduce phase
//   - dt: sdbc row + dw row as float4 pairs
//   - scan: B-row as b128+b64 (p is wave-uniform); ap via exp(Av*sum(dt))
//     instead of per-step product (identical math, -6 VALU mul/step)
__global__ __launch_bounds__(256) void k_conv_scan1(
    const float* __restrict__ xcr,
    const float* __restrict__ cw, const float* __restrict__ cb,
    const float* __restrict__ xw, const float* __restrict__ dw, const float* __restrict__ db,
    const float* __restrict__ alog,
    float* __restrict__ xcc, float* __restrict__ dtb,
    float* __restrict__ Bmb, float* __restrict__ Cmb,
    float* __restrict__ ap, float* __restrict__ hfb){
  __shared__ float smem[9600];           // 38400 B, same as R10
  float* sxr   = smem;                   // 4480 floats [r(35)][n]   (stage->conv)
  float* sdbc4 = smem;                   // 4096 floats [kq][t][o]   (xproj->reduce, aliases sxr)
  float* sdt   = smem;                   // 4096 floats [t][n]       (dt->scan, aliases sdbc4)
  float* sxc   = smem + 4480;            // 4096 floats [t][n]
  float* sdbc  = smem + 8576;            // 1024 floats [t][o32]
  const int bid = blockIdx.x;
  const int sq = bid / NCH, cblk = bid - sq*NCH;
  const int t0 = cblk*CLEN;
  const int lim = (TL - t0 < CLEN) ? (TL - t0) : CLEN;
  const int tid = threadIdx.x;

  // stage: 35 rows x 128 n as float4 (1120 slots)
  for (int i = 0; i < 5; ++i){
    const int e4 = tid + i*256;
    if (e4 < 35*32){
      const int r = e4 >> 5, n4 = (e4 & 31) << 2;
      const int t = t0 - 3 + r;
      float4 v = make_float4(0.f,0.f,0.f,0.f);
      if (t >= 0 && t < TL) v = *(const float4*)(xcr + ((size_t)sq*TL + t)*NF + n4);
      *(float4*)(sxr + r*NF + n4) = v;
    }
  }
  __syncthreads();

  // conv + silu -> sxc (b128) + xcc (global float4). 1024 slots of (r, n4).
  #pragma unroll
  for (int i = 0; i < 4; ++i){
    const int e4 = tid + i*256;
    const int r = e4 >> 5, n4 = (e4 & 31) << 2;
    const float4 c0 = *(const float4*)(cw + (size_t)(n4+0)*4);
    const float4 c1 = *(const float4*)(cw + (size_t)(n4+1)*4);
    const float4 c2 = *(const float4*)(cw + (size_t)(n4+2)*4);
    const float4 c3 = *(const float4*)(cw + (size_t)(n4+3)*4);
    const float4 x0 = *(const float4*)(sxr + (r+0)*NF + n4);
    const float4 x1 = *(const float4*)(sxr + (r+1)*NF + n4);
    const float4 x2 = *(const float4*)(sxr + (r+2)*NF + n4);
    const float4 x3 = *(const float4*)(sxr + (r+3)*NF + n4);
    float4 a = *(const float4*)(cb + n4);
    a.x = fmaf(x3.x, c0.w, fmaf(x2.x, c0.z, fmaf(x1.x, c0.y, fmaf(x0.x, c0.x, a.x))));
    a.y = fmaf(x3.y, c1.w, fmaf(x2.y, c1.z, fmaf(x1.y, c1.y, fmaf(x0.y, c1.x, a.y))));
    a.z = fmaf(x3.z, c2.w, fmaf(x2.z, c2.z, fmaf(x1.z, c2.y, fmaf(x0.z, c2.x, a.z))));
    a.w = fmaf(x3.w, c3.w, fmaf(x2.w, c3.z, fmaf(x1.w, c3.y, fmaf(x0.w, c3.x, a.w))));
    a.x = siluf(a.x); a.y = siluf(a.y); a.z = siluf(a.z); a.w = siluf(a.w);
    *(float4*)(sxc + r*NF + n4) = a;
    if (r < lim) *(float4*)(xcc + ((size_t)sq*TL + t0 + r)*NF + n4) = a;
  }
  __syncthreads();   // sxr reads done -> sdbc4 may overwrite; sxc visible

  // xproj: dbc[t][o] = xc[t][:] @ xw[o][:].  4o x 4t tile, K split 4 ways.
  {
    const int oq = tid & 7, tq = (tid >> 3) & 7, kq = tid >> 6;  // kq == wave id
    const int o0 = oq*4, tb = tq*4, k0 = kq*32;
    float acc[4][4];
    #pragma unroll
    for (int o = 0; o < 4; ++o)
      #pragma unroll
      for (int t = 0; t < 4; ++t) acc[o][t] = 0.f;
    #pragma unroll
    for (int k8 = 0; k8 < 8; ++k8){
      const int kk = k0 + k8*4;
      const float4 w0 = *(const float4*)(xw + (size_t)(o0+0)*NF + kk);
      const float4 w1 = *(const float4*)(xw + (size_t)(o0+1)*NF + kk);
      const float4 w2 = *(const float4*)(xw + (size_t)(o0+2)*NF + kk);
      const float4 w3 = *(const float4*)(xw + (size_t)(o0+3)*NF + kk);
      #pragma unroll
      for (int t = 0; t < 4; ++t){
        const float4 xv = *(const float4*)(sxc + (tb+t)*NF + kk);
        acc[0][t] = fmaf(w0.w, xv.w, fmaf(w0.z, xv.z, fmaf(w0.y, xv.y, fmaf(w0.x, xv.x, acc[0][t]))));
        acc[1][t] = fmaf(w1.w, xv.w, fmaf(w1.z, xv.z, fmaf(w1.y, xv.y, fmaf(w1.x, xv.x, acc[1][t]))));
        acc[2][t] = fmaf(w2.w, xv.w, fmaf(w2.z, xv.z, fmaf(w2.y, xv.y, fmaf(w2.x, xv.x, acc[2][t]))));
        acc[3][t] = fmaf(w3.w, xv.w, fmaf(w3.z, xv.z, fmaf(w3.y, xv.y, fmaf(w3.x, xv.x, acc[3][t]))));
      }
    }
    #pragma unroll
    for (int t = 0; t < 4; ++t){
      float4 v = make_float4(acc[0][t], acc[1][t], acc[2][t], acc[3][t]);
      *(float4*)(sdbc4 + kq*1024 + (tb+t)*32 + o0) = v;
    }
  }
  __syncthreads();

  // reduce 4 K-partials -> sdbc[t][o]
  {
    const int o4 = (tid & 7) << 2, t = tid >> 3;
    float4 s0 = *(const float4*)(sdbc4 +          t*32 + o4);
    float4 s1 = *(const float4*)(sdbc4 + 1024 +   t*32 + o4);
    float4 s2 = *(const float4*)(sdbc4 + 2048 +   t*32 + o4);
    float4 s3 = *(const float4*)(sdbc4 + 3072 +   t*32 + o4);
    s0.x = (s0.x + s1.x) + (s2.x + s3.x);
    s0.y = (s0.y + s1.y) + (s2.y + s3.y);
    s0.z = (s0.z + s1.z) + (s2.z + s3.z);
    s0.w = (s0.w + s1.w) + (s2.w + s3.w);
    *(float4*)(sdbc + t*32 + o4) = s0;
  }
  __syncthreads();   // sdbc4 dead -> sdt may overwrite

  // dt = softplus(dbc[:, :8] @ dw^T + db)  (vectorized row reads)
  #pragma unroll
  for (int i = 0; i < 16; ++i){
    const int e = tid + i*256;
    const int r = e >> 7, n = e & 127;
    const float4 b0 = *(const float4*)(sdbc + r*32);
    const float4 b1 = *(const float4*)(sdbc + r*32 + 4);
    const float4 w0 = *(const float4*)(dw + (size_t)n*8);
    const float4 w1 = *(const float4*)(dw + (size_t)n*8 + 4);
    float acc = db[n];
    acc = fmaf(b0.x, w0.x, acc); acc = fmaf(b0.y, w0.y, acc);
    acc = fmaf(b0.z, w0.z, acc); acc = fmaf(b0.w, w0.w, acc);
    acc = fmaf(b1.x, w1.x, acc); acc = fmaf(b1.y, w1.y, acc);
    acc = fmaf(b1.z, w1.z, acc); acc = fmaf(b1.w, w1.w, acc);
    const float dtv = softplusf(acc);
    sdt[e] = dtv;
    if (e < lim*NF) dtb[((size_t)sq*TL + t0)*NF + e] = dtv;
  }
  // B/C global writes
  for (int e = tid; e < CLEN*2*SD; e += 256){
    int r = e / (2*SD), c = e - r*2*SD;
    if (r < lim){
      float v = sdbc[r*32 + 8 + c];
      size_t tok = (size_t)sq*TL + t0 + r;
      if (c < SD) Bmb[tok*SD + c] = v;
      else        Cmb[tok*SD + (c - SD)] = v;
    }
  }
  __syncthreads();

  // scan pass 1: per-chunk h and cumulative dA product (via exp(Av*sum dt))
  {
    const int n = tid & 127, p = tid >> 7;   // p is wave-uniform
    float Av[6], h[6];
    #pragma unroll
    for (int s = 0; s < 6; ++s){
      Av[s] = -__expf(alog[(size_t)n*SD + p*6 + s]);
      h[s] = 0.f;
    }
    float dts = 0.f;
    for (int tt = 0; tt < lim; ++tt){
      const float dtv = sdt[tt*NF + n];
      const float dx  = dtv * sxc[tt*NF + n];
      dts += dtv;
      float Bv[6];
      const float* br = sdbc + tt*32 + 8 + p*6;
      if (p == 0){
        const float4 a = *(const float4*)br;        // cols 8..11 (16B aligned)
        const float2 b = *(const float2*)(br + 4);  // cols 12..13
        Bv[0]=a.x; Bv[1]=a.y; Bv[2]=a.z; Bv[3]=a.w; Bv[4]=b.x; Bv[5]=b.y;
      } else {
        const float2 a = *(const float2*)br;        // cols 14..15
        const float4 b = *(const float4*)(br + 2);  // cols 16..19 (16B aligned)
        Bv[0]=a.x; Bv[1]=a.y; Bv[2]=b.x; Bv[3]=b.y; Bv[4]=b.z; Bv[5]=b.w;
      }
      #pragma unroll
      for (int s = 0; s < 6; ++s){
        const float dA = __expf(dtv*Av[s]);
        h[s] = fmaf(dA, h[s], dx*Bv[s]);
      }
    }
    const size_t base = (size_t)bid*SD*NF + n;
    #pragma unroll
    for (int s = 0; s < 6; ++s){
      ap [base + (p*6+s)*NF] = __expf(Av[s]*dts);
      hfb[base + (p*6+s)*NF] = h[s];
    }
  }
}

// ---- K3b: sequential combine across chunks
__global__ __launch_bounds__(128) void k_scan_combine(
    const float* __restrict__ ap, const float* __restrict__ hfb, float* __restrict__ hinit){
  const int sq = blockIdx.x;
  const int n = threadIdx.x;
  float h[SD];
  #pragma unroll
  for (int s = 0; s < SD; ++s) h[s] = 0.f;
  for (int c = 0; c < NCH; ++c){
    const size_t base = ((size_t)sq*NCH + c)*SD*NF + n;
    #pragma unroll
    for (int s = 0; s < SD; ++s){
      hinit[base + s*NF] = h[s];
      h[s] = fmaf(ap[base + s*NF], h[s], hfb[base + s*NF]);
    }
  }
}

// ---- K3c: scan pass 2 + gate: yb = (y + Dv*xc)*silu(z)
__global__ __launch_bounds__(128) void k_scan_pass2(
    const float* __restrict__ dtb, const float* __restrict__ xcc,
    const float* __restrict__ Bmb, const float* __restrict__ Cmb,
    const float* __restrict__ alog, const float* __restrict__ hinit,
    const float* __restrict__ zb, const float* __restrict__ Dv,
    float* __restrict__ yb){
  const int bid = blockIdx.x;
  const int sq = bid / NCH, c = bid - sq*NCH;
  const int t0 = c*CLEN;
  const int lim = (TL - t0 < CLEN) ? (TL - t0) : CLEN;
  const int n = threadIdx.x;
  const float4* A4 = (const float4*)(alog + (size_t)n*SD);
  float4 Aa = A4[0], Ab = A4[1], Ac = A4[2];
  float Av[SD] = {Aa.x,Aa.y,Aa.z,Aa.w, Ab.x,Ab.y,Ab.z,Ab.w, Ac.x,Ac.y,Ac.z,Ac.w};
  #pragma unroll
  for (int s = 0; s < SD; ++s) Av[s] = -__expf(Av[s]);
  const float dvn = Dv[n];
  float h[SD];
  const size_t hbase = (size_t)bid*SD*NF + n;
  #pragma unroll
  for (int s = 0; s < SD; ++s) h[s] = hinit[hbase + s*NF];
  const size_t tok0 = (size_t)sq*TL + t0;
  for (int tt = 0; tt < lim; ++tt){
    const size_t tok = tok0 + tt;
    float dtv = dtb[tok*NF + n];
    float xcv = xcc[tok*NF + n];
    float dx  = dtv * xcv;
    const float4* B4 = (const float4*)(Bmb + tok*SD);
    const float4* C4 = (const float4*)(Cmb + tok*SD);
    float4 Ba=B4[0], Bb=B4[1], Bc=B4[2];
    float4 Ca=C4[0], Cb=C4[1], Cc=C4[2];
    float Bv[SD] = {Ba.x,Ba.y,Ba.z,Ba.w, Bb.x,Bb.y,Bb.z,Bb.w, Bc.x,Bc.y,Bc.z,Bc.w};
    float Cv[SD] = {Ca.x,Ca.y,Ca.z,Ca.w, Cb.x,Cb.y,Cb.z,Cb.w, Cc.x,Cc.y,Cc.z,Cc.w};
    float yv = 0.f;
    #pragma unroll
    for (int s = 0; s < SD; ++s){
      float dA = __expf(dtv*Av[s]);
      h[s] = fmaf(dA, h[s], dx*Bv[s]);
      yv = fmaf(h[s], Cv[s], yv);
    }
    float zv = zb[tok*NF + n];
    yb[tok*NF + n] = fmaf(dvn, xcv, yv) * siluf(zv);
  }
}

// ---- K4 (known-good): seq += yb @ ow^T + ob. 64 tokens/block, 256 threads, 4ox8t.
__global__ __launch_bounds__(256) void k_gate_out(
    const float* __restrict__ yb,
    const float* __restrict__ ow, const float* __restrict__ ob,
    float* __restrict__ seq){
  __shared__ float xs[NF*XSP];    // [n][t]
  __shared__ float wl[32*GWS];    // [kl][o]
  const int tid = threadIdx.x;
  const int tok0 = blockIdx.x * MT;

  #pragma unroll
  for (int i = 0; i < 8; ++i){
    const int e4 = tid + i*256;
    const int nq = e4 & 31, r = e4 >> 5;
    const int tok = tok0 + r;
    float4 v = make_float4(0.f,0.f,0.f,0.f);
    if (tok < NTOK) v = *(const float4*)(yb + (size_t)tok*NF + nq*4);
    xs[(nq*4+0)*XSP + r] = v.x;
    xs[(nq*4+1)*XSP + r] = v.y;
    xs[(nq*4+2)*XSP + r] = v.z;
    xs[(nq*4+3)*XSP + r] = v.w;
  }

  const int o4 = tid & 31, t8 = tid >> 5;
  float acc[4][8];
  #pragma unroll
  for (int o = 0; o < 4; ++o)
    #pragma unroll
    for (int t = 0; t < 8; ++t) acc[o][t] = 0.f;

  for (int kt = 0; kt < 4; ++kt){
    __syncthreads();
    {
      const int ch = tid & 7, row = tid >> 3;
      #pragma unroll
      for (int p = 0; p < 4; ++p){
        const int o = row + 32*p;
        const float4 w4 = *(const float4*)(ow + (size_t)o*NF + kt*32 + ch*4);
        const int kl = ch*4;
        wl[(kl+0)*GWS + o] = w4.x;
        wl[(kl+1)*GWS + o] = w4.y;
        wl[(kl+2)*GWS + o] = w4.z;
        wl[(kl+3)*GWS + o] = w4.w;
      }
    }
    __syncthreads();
    for (int kl = 0; kl < 32; ++kl){
      const int kg = kt*32 + kl;
      const float4 wa = *(const float4*)&wl[kl*GWS + o4*4];
      const float4 xa = *(const float4*)&xs[kg*XSP + t8*8];
      const float4 xb = *(const float4*)&xs[kg*XSP + t8*8 + 4];
      const float wv[4] = {wa.x,wa.y,wa.z,wa.w};
      const float xv[8] = {xa.x,xa.y,xa.z,xa.w, xb.x,xb.y,xb.z,xb.w};
      #pragma unroll
      for (int o = 0; o < 4; ++o)
        #pragma unroll
        for (int t = 0; t < 8; ++t)
          acc[o][t] = fmaf(wv[o], xv[t], acc[o][t]);
    }
  }

  float bo[4];
  #pragma unroll
  for (int i = 0; i < 4; ++i) bo[i] = ob[o4*4 + i];
  #pragma unroll
  for (int j = 0; j < 8; ++j){
    const int tok = tok0 + t8*8 + j;
    if (tok >= NTOK) break;
    float* dst = seq + (size_t)tok*NF + o4*4;
    float4 s0 = *(float4*)dst;
    s0.x += acc[0][j]+bo[0]; s0.y += acc[1][j]+bo[1];
    s0.z += acc[2][j]+bo[2]; s0.w += acc[3][j]+bo[3];
    *(float4*)dst = s0;
  }
}

// ---- K5a: cross = main @ cb_w^T + cb_b. Exact k_gate_out structure; seq gather staging.
__global__ __launch_bounds__(256) void k_cross_gemm(
    const float* __restrict__ seq,
    const float* __restrict__ cbw, const float* __restrict__ cbb,
    float* __restrict__ cross){
  __shared__ float xs[NF*XSP];    // [n][t]
  __shared__ float wl[32*GWS];    // [kl][o]
  const int tid = threadIdx.x;
  const int tok0 = blockIdx.x * MT;

  #pragma unroll
  for (int i = 0; i < 8; ++i){
    const int e4 = tid + i*256;
    const int nq = e4 & 31, r = e4 >> 5;
    const int tok = tok0 + r;
    float4 v = make_float4(0.f,0.f,0.f,0.f);
    if (tok < NTOK){
      int b = tok / 30000, rr = tok - b*30000;
      int t = rr / 30, k = rr - t*30;
      v = *(const float4*)(seq + ((size_t)(b*30 + k)*TL + t)*NF + nq*4);
    }
    xs[(nq*4+0)*XSP + r] = v.x;
    xs[(nq*4+1)*XSP + r] = v.y;
    xs[(nq*4+2)*XSP + r] = v.z;
    xs[(nq*4+3)*XSP + r] = v.w;
  }

  const int o4 = tid & 31, t8 = tid >> 5;
  float acc[4][8];
  #pragma unroll
  for (int o = 0; o < 4; ++o)
    #pragma unroll
    for (int t = 0; t < 8; ++t) acc[o][t] = 0.f;

  for (int kt = 0; kt < 4; ++kt){
    __syncthreads();
    {
      const int ch = tid & 7, row = tid >> 3;
      #pragma unroll
      for (int p = 0; p < 4; ++p){
        const int o = row + 32*p;
        const float4 w4 = *(const float4*)(cbw + (size_t)o*NF + kt*32 + ch*4);
        const int kl = ch*4;
        wl[(kl+0)*GWS + o] = w4.x;
        wl[(kl+1)*GWS + o] = w4.y;
        wl[(kl+2)*GWS + o] = w4.z;
        wl[(kl+3)*GWS + o] = w4.w;
      }
    }
    __syncthreads();
    for (int kl = 0; kl < 32; ++kl){
      const int kg = kt*32 + kl;
      const float4 wa = *(const float4*)&wl[kl*GWS + o4*4];
      const float4 xa = *(const float4*)&xs[kg*XSP + t8*8];
      const float4 xb = *(const float4*)&xs[kg*XSP + t8*8 + 4];
      const float wv[4] = {wa.x,wa.y,wa.z,wa.w};
      const float xv[8] = {xa.x,xa.y,xa.z,xa.w, xb.x,xb.y,xb.z,xb.w};
      #pragma unroll
      for (int o = 0; o < 4; ++o)
        #pragma unroll
        for (int t = 0; t < 8; ++t)
          acc[o][t] = fmaf(wv[o], xv[t], acc[o][t]);
    }
  }

  float bo[4];
  #pragma unroll
  for (int i = 0; i < 4; ++i) bo[i] = cbb[o4*4 + i];
  #pragma unroll
  for (int j = 0; j < 8; ++j){
    const int tok = tok0 + t8*8 + j;
    if (tok >= NTOK) break;
    float4 s0;
    s0.x = acc[0][j]+bo[0]; s0.y = acc[1][j]+bo[1];
    s0.z = acc[2][j]+bo[2]; s0.w = acc[3][j]+bo[3];
    *(float4*)(cross + (size_t)tok*NF + o4*4) = s0;
  }
}

// ---- K5b: LN1 -> gelu -> +main -> LN2 -> transposed write. 32 tokens/block.
__global__ __launch_bounds__(256) void k_cross_ln(
    const float* __restrict__ seq, const float* __restrict__ cross,
    const float* __restrict__ clnw, const float* __restrict__ clnb,
    const float* __restrict__ flnw, const float* __restrict__ flnb,
    float* __restrict__ out){
  __shared__ float fs[32*LNP];
  const int tid = threadIdx.x;
  const int tok0 = blockIdx.x * 32;
  const int j16 = tid >> 4, l16 = tid & 15;

  for (int it = 0; it < 2; ++it){
    const int jj = j16 + 16*it;
    const int tok = tok0 + jj;
    const int b = tok / 30000, rr = tok - b*30000;
    const int t = rr / 30, k = rr - t*30;
    const float* cp = cross + (size_t)tok*NF;
    const float* mp = seq + ((size_t)(b*30 + k)*TL + t)*NF;
    float cv[8]; float s = 0.f, s2 = 0.f;
    #pragma unroll
    for (int i = 0; i < 8; ++i){
      float f = cp[l16 + 16*i]; cv[i] = f; s += f; s2 += f*f;
    }
    #pragma unroll
    for (int m = 1; m < 16; m <<= 1){ s += __shfl_xor(s, m, 64); s2 += __shfl_xor(s2, m, 64); }
    float mu = s * (1.f/128.f);
    float rs = rsqrtf(s2*(1.f/128.f) - mu*mu + 1e-5f);
    float rv[8]; float rsum = 0.f, rsum2 = 0.f;
    #pragma unroll
    for (int i = 0; i < 8; ++i){
      int n = l16 + 16*i;
      float cn = (cv[i] - mu)*rs*clnw[n] + clnb[n];
      float g = 0.5f*cn*(1.f + erff(cn*0.70710678118f));
      float res = mp[n] + g;
      rv[i] = res; rsum += res; rsum2 += res*res;
    }
    #pragma unroll
    for (int m = 1; m < 16; m <<= 1){ rsum += __shfl_xor(rsum, m, 64); rsum2 += __shfl_xor(rsum2, m, 64); }
    float mu2 = rsum * (1.f/128.f);
    float rs2 = rsqrtf(rsum2*(1.f/128.f) - mu2*mu2 + 1e-5f);
    #pragma unroll
    for (int i = 0; i < 8; ++i){
      int n = l16 + 16*i;
      fs[jj*LNP + n] = (rv[i] - mu2)*rs2*flnw[n] + flnb[n];
    }
  }
  __syncthreads();

  #pragma unroll
  for (int i = 0; i < 16; ++i){
    const int e = tid + i*256;
    const int j = e & 31, n = e >> 5;
    const int tok = tok0 + j;
    const int b = tok / 30000, rr = tok - b*30000;
    out[(size_t)(b*NF + n)*30000 + rr] = fs[j*LNP + n];
  }
}

extern "C" void kernel_launch(void* const* d_in, const int* in_sizes, int n_in,
                              void* d_out, int out_size, void* d_ws, size_t ws_size,
                              hipStream_t stream){
  const float* x       = (const float*)d_in[0];
  const float* ln_w    = (const float*)d_in[1];
  const float* ln_b    = (const float*)d_in[2];
  const float* in_w    = (const float*)d_in[3];
  const float* in_b    = (const float*)d_in[4];
  const float* conv_w  = (const float*)d_in[5];
  const float* conv_b  = (const float*)d_in[6];
  const float* xp_w    = (const float*)d_in[7];
  const float* dtp_w   = (const float*)d_in[8];
  const float* dtp_b   = (const float*)d_in[9];
  const float* A_log   = (const float*)d_in[10];
  const float* Dv      = (const float*)d_in[11];
  const float* out_w   = (const float*)d_in[12];
  const float* out_b   = (const float*)d_in[13];
  const float* cb_w    = (const float*)d_in[14];
  const float* cb_b    = (const float*)d_in[15];
  const float* cb_ln_w = (const float*)d_in[16];
  const float* cb_ln_b = (const float*)d_in[17];
  const float* fin_ln_w= (const float*)d_in[18];
  const float* fin_ln_b= (const float*)d_in[19];
  float* out = (float*)d_out;

  const size_t SEQSZ = (size_t)BKS*TL*NF;        // 7,680,000 floats
  const size_t CHSZ  = (size_t)BKS*NF*NCH*SD;    // 2,949,120 floats (NCH=32)
  const size_t BASE  = 6*SEQSZ + 2*(size_t)BKS*TL*SD;   // ~190MB
  float* ws  = (float*)d_ws;
  float* seq = ws;
  float* xcr = ws + SEQSZ;
  float* zb  = ws + 2*SEQSZ;
  float* xcc = ws + 3*SEQSZ;
  float* dtb = ws + 4*SEQSZ;
  float* yb  = ws + 5*SEQSZ;
  float* Bmb = ws + 6*SEQSZ;
  float* Cmb = Bmb + (size_t)BKS*TL*SD;
  if (ws_size < BASE*sizeof(float)) return;

  // Liveness aliasing: ap/hfb -> yb region (2*CHSZ = 5.9M <= SEQSZ); hinit -> xcr;
  // cross -> dtb (dead after last pass2).
  float* ap    = yb;
  float* hfb   = yb + CHSZ;
  float* hinit = xcr;
  float* cross = dtb;

  k_ingest<<<2*TL, 256, 0, stream>>>(x, seq);
  for (int l = 0; l < 4; ++l){
    k_ln_inproj<<<NBLK, 256, 0, stream>>>(seq, ln_w + l*NF, ln_b + l*NF,
        in_w + (size_t)l*2*NF*NF, in_b + l*2*NF, xcr, zb);
    k_conv_scan1<<<BKS*NCH, 256, 0, stream>>>(xcr, conv_w + (size_t)l*NF*4, conv_b + l*NF,
        xp_w + (size_t)l*32*NF, dtp_w + (size_t)l*NF*RD, dtp_b + l*NF,
        A_log + (size_t)l*NF*SD, xcc, dtb, Bmb, Cmb, ap, hfb);
    k_scan_combine<<<BKS, NF, 0, stream>>>(ap, hfb, hinit);
    k_scan_pass2<<<BKS*NCH, NF, 0, stream>>>(dtb, xcc, Bmb, Cmb, A_log + (size_t)l*NF*SD,
        hinit, zb, Dv + l*NF, yb);
    k_gate_out<<<NBLK, 256, 0, stream>>>(yb, out_w + (size_t)l*NF*NF, out_b + l*NF, seq);
  }
  k_cross_gemm<<<NBLK, 256, 0, stream>>>(seq, cb_w, cb_b, cross);
  k_cross_ln<<<NTOK/32, 256, 0, stream>>>(seq, cross, cb_ln_w, cb_ln_b, fin_ln_w, fin_ln_b, out);
}